// Round 12
// baseline (1030.613 us; speedup 1.0000x reference)
//
#include <hip/hip_runtime.h>
#include <cstddef>

// Problem dims
#define B_  64
#define R_  49
#define F_  512
#define H_  512
#define V_  10000
#define TT  32
#define TS  31

typedef _Float16 half8 __attribute__((ext_vector_type(8)));
typedef float    f32x4 __attribute__((ext_vector_type(4)));

__device__ __forceinline__ float fsigm(float x) { return 1.0f / (1.0f + __expf(-x)); }
__device__ __forceinline__ float ftanh(float x) { return 1.0f - 2.0f / (__expf(2.0f * x) + 1.0f); }

__device__ __forceinline__ half8 cvt8(float4 a, float4 b) {
    half8 o = { (_Float16)a.x, (_Float16)a.y, (_Float16)a.z, (_Float16)a.w,
                (_Float16)b.x, (_Float16)b.y, (_Float16)b.z, (_Float16)b.w };
    return o;
}

// ---------------------------------------------------------------------------
// Generic fp32 NT GEMM (h0/c0 only). Optional Ct: also store C^T with
// Ct[(size_t)n * ldct + m]  (used to write hT[j][b] directly for h0).
// ---------------------------------------------------------------------------
__global__ __launch_bounds__(256) void gemm_nt_f32(
    const float* __restrict__ A, int lda,
    const float* __restrict__ Bm, int ldb,
    const float* __restrict__ bias1, const float* __restrict__ bias2,
    float* __restrict__ C, int ldc, int M, int N, int K,
    float* __restrict__ Ct, int ldct)
{
    __shared__ __align__(16) float As[16][68];
    __shared__ __align__(16) float Bs[16][68];
    const int tid = threadIdx.x;
    const int m0 = blockIdx.y * 64, n0 = blockIdx.x * 64;
    const int tr = tid >> 4, tc = tid & 15;
    const int lrow = tid >> 2, lk4 = (tid & 3) * 4;
    const bool am = (m0 + lrow) < M;
    const bool bn = (n0 + lrow) < N;
    const float* aptr = A + (size_t)(m0 + lrow) * lda + lk4;
    const float* bptr = Bm + (size_t)(n0 + lrow) * ldb + lk4;
    float acc[4][4] = {};

    for (int k0 = 0; k0 < K; k0 += 16) {
        float4 av = make_float4(0.f, 0.f, 0.f, 0.f);
        float4 bv = make_float4(0.f, 0.f, 0.f, 0.f);
        if (am) av = *(const float4*)(aptr + k0);
        if (bn) bv = *(const float4*)(bptr + k0);
        __syncthreads();
        As[lk4 + 0][lrow] = av.x; As[lk4 + 1][lrow] = av.y;
        As[lk4 + 2][lrow] = av.z; As[lk4 + 3][lrow] = av.w;
        Bs[lk4 + 0][lrow] = bv.x; Bs[lk4 + 1][lrow] = bv.y;
        Bs[lk4 + 2][lrow] = bv.z; Bs[lk4 + 3][lrow] = bv.w;
        __syncthreads();
#pragma unroll
        for (int kk = 0; kk < 16; ++kk) {
            float4 a = *(const float4*)&As[kk][tr * 4];
            float4 b = *(const float4*)&Bs[kk][tc * 4];
            acc[0][0] += a.x * b.x; acc[0][1] += a.x * b.y; acc[0][2] += a.x * b.z; acc[0][3] += a.x * b.w;
            acc[1][0] += a.y * b.x; acc[1][1] += a.y * b.y; acc[1][2] += a.y * b.z; acc[1][3] += a.y * b.w;
            acc[2][0] += a.z * b.x; acc[2][1] += a.z * b.y; acc[2][2] += a.z * b.z; acc[2][3] += a.z * b.w;
            acc[3][0] += a.w * b.x; acc[3][1] += a.w * b.y; acc[3][2] += a.w * b.z; acc[3][3] += a.w * b.w;
        }
    }
#pragma unroll
    for (int i = 0; i < 4; ++i) {
        int m = m0 + tr * 4 + i;
        if (m >= M) continue;
#pragma unroll
        for (int j = 0; j < 4; ++j) {
            int n = n0 + tc * 4 + j;
            if (n >= N) continue;
            float v = acc[i][j];
            if (bias1) v += bias1[n];
            if (bias2) v += bias2[n];
            if (C)  C[(size_t)m * ldc + n] = v;
            if (Ct) Ct[(size_t)n * ldct + m] = v;
        }
    }
}

__global__ __launch_bounds__(256) void k_avg(const float* __restrict__ feat,
                                             float* __restrict__ avg)
{
    int id = blockIdx.x * 256 + threadIdx.x;
    int b = id >> 9, f = id & 511;
    const float* p = feat + (size_t)b * R_ * F_ + f;
    float s = 0.f;
#pragma unroll 7
    for (int r = 0; r < R_; ++r) s += p[r * F_];
    avg[id] = s * (1.0f / 49.0f);
}

// ---------------------------------------------------------------------------
// Mixed NT GEMM: A fp32 [M,512] (lda), B fp32 [N,512] (ldb), cvt->f16 in-kernel,
// MFMA 16x16x32, out f16 (Ch) or fp32 (Cf), + bias1 + bias2.
// ---------------------------------------------------------------------------
__global__ __launch_bounds__(256) void gemm_nt_ff(
    const float* __restrict__ A, int lda,
    const float* __restrict__ Bm, int ldb,
    const float* __restrict__ bias1, const float* __restrict__ bias2,
    float* __restrict__ Cf, _Float16* __restrict__ Ch, int N)
{
    __shared__ __align__(16) _Float16 As[64][40];
    __shared__ __align__(16) _Float16 Bs[64][40];
    const int tid = threadIdx.x;
    const int w = tid >> 6, lane = tid & 63;
    const int m0 = blockIdx.y * 64, n0 = blockIdx.x * 64;
    const int srow = tid >> 2, sko = (tid & 3) * 8;
    const int fr = lane & 15, oct = lane >> 4;

    f32x4 acc[4];
#pragma unroll
    for (int nt = 0; nt < 4; ++nt) acc[nt] = (f32x4){0.f, 0.f, 0.f, 0.f};

    const float* ap = A + (size_t)(m0 + srow) * lda + sko;
    const float* bp = Bm + (size_t)(n0 + srow) * ldb + sko;

    for (int k0 = 0; k0 < 512; k0 += 32) {
        float4 a0 = *(const float4*)(ap + k0);
        float4 a1 = *(const float4*)(ap + k0 + 4);
        float4 b0 = *(const float4*)(bp + k0);
        float4 b1 = *(const float4*)(bp + k0 + 4);
        __syncthreads();
        *(half8*)&As[srow][sko] = cvt8(a0, a1);
        *(half8*)&Bs[srow][sko] = cvt8(b0, b1);
        __syncthreads();
        half8 af = *(const half8*)&As[w * 16 + fr][oct * 8];
#pragma unroll
        for (int nt = 0; nt < 4; ++nt) {
            half8 bf = *(const half8*)&Bs[nt * 16 + fr][oct * 8];
            acc[nt] = __builtin_amdgcn_mfma_f32_16x16x32_f16(af, bf, acc[nt], 0, 0, 0);
        }
    }
#pragma unroll
    for (int nt = 0; nt < 4; ++nt) {
        int nn = n0 + nt * 16 + fr;
        float bb = bias1 ? bias1[nn] : 0.f;
        if (bias2) bb += bias2[nn];
#pragma unroll
        for (int r = 0; r < 4; ++r) {
            int mm = m0 + w * 16 + oct * 4 + r;
            float v = acc[nt][r] + bb;
            if (Cf) Cf[(size_t)mm * N + nn] = v;
            else    Ch[(size_t)mm * N + nn] = (_Float16)v;
        }
    }
}

// ---------------------------------------------------------------------------
// Logits GEMM, XCD-swizzled, 64m x 256n tile: A f16 [1984,512],
// B fp32 [N,512] cvt-in-kernel. Wave w owns m-frag w x all 16 n-frags.
// nsup = xcd + 8*(g/31) (bijective over 40 supertiles), mtile = g%31.
// ---------------------------------------------------------------------------
#define MT_  31
#define NSUP_ 40
__global__ __launch_bounds__(256) void gemm_nt_hf_swz(
    const _Float16* __restrict__ A, const float* __restrict__ Bm,
    const float* __restrict__ bias, float* __restrict__ C, int N)
{
    const int L = blockIdx.x;
    const int xcd = L & 7, g = L >> 3;
    const int nsup = xcd + 8 * (g / MT_);
    const int mtile = g % MT_;
    if (nsup >= NSUP_) return;

    __shared__ __align__(16) _Float16 As[64][40];
    __shared__ __align__(16) _Float16 Bs[256][40];
    const int tid = threadIdx.x;
    const int w = tid >> 6, lane = tid & 63;
    const int m0 = mtile * 64, n0 = nsup * 256;
    const int srow = tid >> 2, sko = (tid & 3) * 8;
    const int fr = lane & 15, oct = lane >> 4;

    f32x4 acc[16];
#pragma unroll
    for (int nt = 0; nt < 16; ++nt) acc[nt] = (f32x4){0.f, 0.f, 0.f, 0.f};

    const _Float16* ap = A + (size_t)(m0 + srow) * 512 + sko;
    bool bok[4];
    const float* bp[4];
#pragma unroll
    for (int q = 0; q < 4; ++q) {
        int row = n0 + q * 64 + srow;
        bok[q] = row < N;
        bp[q] = Bm + (size_t)row * 512 + sko;
    }

    for (int k0 = 0; k0 < 512; k0 += 32) {
        half8 av = *(const half8*)(ap + k0);
        float4 b0[4], b1[4];
#pragma unroll
        for (int q = 0; q < 4; ++q) {
            b0[q] = make_float4(0.f, 0.f, 0.f, 0.f);
            b1[q] = b0[q];
            if (bok[q]) { b0[q] = *(const float4*)(bp[q] + k0);
                          b1[q] = *(const float4*)(bp[q] + k0 + 4); }
        }
        __syncthreads();
        *(half8*)&As[srow][sko] = av;
#pragma unroll
        for (int q = 0; q < 4; ++q)
            *(half8*)&Bs[q * 64 + srow][sko] = cvt8(b0[q], b1[q]);
        __syncthreads();
        half8 af = *(const half8*)&As[w * 16 + fr][oct * 8];
#pragma unroll
        for (int nt = 0; nt < 16; ++nt) {
            half8 bf = *(const half8*)&Bs[nt * 16 + fr][oct * 8];
            acc[nt] = __builtin_amdgcn_mfma_f32_16x16x32_f16(af, bf, acc[nt], 0, 0, 0);
        }
    }
#pragma unroll
    for (int nt = 0; nt < 16; ++nt) {
        int nn = n0 + nt * 16 + fr;
        if (nn >= N) continue;
        float bb = bias[nn];
#pragma unroll
        for (int r = 0; r < 4; ++r) {
            int mm = m0 + w * 16 + oct * 4 + r;
            C[(size_t)mm * N + nn] = acc[nt][r] + bb;
        }
    }
}

// ---------------------------------------------------------------------------
// K_A (j-parallel, 256 blocks x 256 threads): block bid owns W_hh rows
// 8bid..8bid+7 and W_dec rows 2bid..2bid+1. (R10-exact version.)
// ---------------------------------------------------------------------------
__global__ __launch_bounds__(256) void kA(
    const float* __restrict__ hT, const float* __restrict__ W_dec,
    const float* __restrict__ b_dec, const float* __restrict__ W_hh,
    float* __restrict__ dTb, float* __restrict__ gH)
{
    __shared__ __align__(16) float wpan[10 * 512];   // 20 KB
    __shared__ float red[4][640];                    // 10 KB
    const int tid = threadIdx.x, bid = blockIdx.x;
    const int lane = tid & 63, w = tid >> 6;

    for (int idx = tid * 4; idx < 10 * 512; idx += 1024) {
        int r = idx >> 9, k = idx & 511;
        const float* src = (r < 8) ? &W_hh[(size_t)(8 * bid + r) * 512 + k]
                                   : &W_dec[(size_t)(2 * bid + r - 8) * 512 + k];
        *(float4*)&wpan[idx] = *(const float4*)src;
    }
    __syncthreads();
    float acc[10] = {};
    for (int j4 = 32 * w; j4 < 32 * w + 32; ++j4) {
        int j = j4 * 4;
        float x0 = hT[(j + 0) * 64 + lane];
        float x1 = hT[(j + 1) * 64 + lane];
        float x2 = hT[(j + 2) * 64 + lane];
        float x3 = hT[(j + 3) * 64 + lane];
#pragma unroll
        for (int r = 0; r < 10; ++r) {
            float4 wv = *(const float4*)&wpan[r * 512 + j];
            acc[r] += wv.x * x0 + wv.y * x1 + wv.z * x2 + wv.w * x3;
        }
    }
#pragma unroll
    for (int r = 0; r < 10; ++r) red[w][r * 64 + lane] = acc[r];
    __syncthreads();
    for (int o = tid; o < 640; o += 256) {
        int r = o >> 6, b = o & 63;
        float s = red[0][o] + red[1][o] + red[2][o] + red[3][o];
        if (r < 8) gH[(size_t)b * 2048 + 8 * bid + r] = s;
        else       dTb[(size_t)b * 512 + 2 * bid + (r - 8)] = s + b_dec[2 * bid + r - 8];
    }
}

// ---------------------------------------------------------------------------
// K_B (b-parallel, 64 blocks x 256 threads): e/softmax/alpha; gates =
// sum_r alpha_r*G[b,r,:] + gH + embg; LSTM pointwise. (R10-exact version.)
// ---------------------------------------------------------------------------
__global__ __launch_bounds__(256) void kB(
    const float* __restrict__ dTb, const _Float16* __restrict__ encatH,
    const float* __restrict__ v_w, const float* __restrict__ v_b,
    const _Float16* __restrict__ G, const float* __restrict__ gH,
    const _Float16* __restrict__ embgH, float* __restrict__ cB,
    float* __restrict__ hTn, _Float16* __restrict__ Hh, int t)
{
    __shared__ float da[512];
    __shared__ float esh[52];
    __shared__ float al[52];
    __shared__ float gsm[2048];
    const int tid = threadIdx.x, b = blockIdx.x;
    const int lane = tid & 63, w = tid >> 6;

    da[tid]       = dTb[(size_t)b * 512 + tid];
    da[tid + 256] = dTb[(size_t)b * 512 + tid + 256];
    __syncthreads();

    for (int r = w; r < R_; r += 4) {
        const _Float16* er = encatH + ((size_t)b * R_ + r) * 512;
        float s = 0.f;
#pragma unroll
        for (int i = 0; i < 8; ++i) {
            int j = i * 64 + lane;
            s += ftanh((float)er[j] + da[j]) * v_w[j];
        }
#pragma unroll
        for (int off = 32; off; off >>= 1) s += __shfl_down(s, off, 64);
        if (lane == 0) esh[r] = s + v_b[0];
    }
    __syncthreads();
    if (tid < 64) {
        float x = (lane < R_) ? esh[lane] : -1e30f;
        float mx = x;
#pragma unroll
        for (int off = 32; off; off >>= 1) mx = fmaxf(mx, __shfl_xor(mx, off, 64));
        float ex = (lane < R_) ? __expf(x - mx) : 0.f;
        float sm = ex;
#pragma unroll
        for (int off = 32; off; off >>= 1) sm += __shfl_xor(sm, off, 64);
        if (lane < R_) al[lane] = ex / sm;
    }
    __syncthreads();

    // gates: rows [tid*8, tid*8+8)
    {
        const int r0 = tid * 8;
        float a8[8] = {};
        const _Float16* gp = G + ((size_t)b * R_) * 2048 + r0;
        for (int r = 0; r < R_; ++r) {
            half8 g8 = *(const half8*)(gp + (size_t)r * 2048);
            float ar = al[r];
#pragma unroll
            for (int u = 0; u < 8; ++u) a8[u] += ar * (float)g8[u];
        }
        float4 gh0 = *(const float4*)&gH[(size_t)b * 2048 + r0];
        float4 gh1 = *(const float4*)&gH[(size_t)b * 2048 + r0 + 4];
        half8 e8 = *(const half8*)&embgH[((size_t)b * TT + t) * 2048 + r0];
        gsm[r0 + 0] = a8[0] + gh0.x + (float)e8[0];
        gsm[r0 + 1] = a8[1] + gh0.y + (float)e8[1];
        gsm[r0 + 2] = a8[2] + gh0.z + (float)e8[2];
        gsm[r0 + 3] = a8[3] + gh0.w + (float)e8[3];
        gsm[r0 + 4] = a8[4] + gh1.x + (float)e8[4];
        gsm[r0 + 5] = a8[5] + gh1.y + (float)e8[5];
        gsm[r0 + 6] = a8[6] + gh1.z + (float)e8[6];
        gsm[r0 + 7] = a8[7] + gh1.w + (float)e8[7];
    }
    __syncthreads();

#pragma unroll
    for (int p = 0; p < 2; ++p) {
        int j = tid + p * 256;
        float ig = fsigm(gsm[j]);
        float fg = fsigm(gsm[512 + j]);
        float gg = ftanh(gsm[1024 + j]);
        float og = fsigm(gsm[1536 + j]);
        float c  = cB[(size_t)b * 512 + j];
        float cn = fg * c + ig * gg;
        float hn = og * ftanh(cn);
        cB[(size_t)b * 512 + j] = cn;
        hTn[(size_t)j * 64 + b] = hn;
        Hh[((size_t)b * TS + t) * 512 + j] = (_Float16)hn;
    }
}

// ---------------------------------------------------------------------------
extern "C" void kernel_launch(void* const* d_in, const int* in_sizes, int n_in,
                              void* d_out, int out_size, void* d_ws, size_t ws_size,
                              hipStream_t stream)
{
    (void)in_sizes; (void)n_in; (void)out_size; (void)ws_size;
    const float* feat     = (const float*)d_in[0];
    const float* caps     = (const float*)d_in[1];
    const float* W_enc    = (const float*)d_in[2];
    const float* b_enc    = (const float*)d_in[3];
    const float* W_dec    = (const float*)d_in[4];
    const float* b_dec    = (const float*)d_in[5];
    const float* v_w      = (const float*)d_in[6];
    const float* v_b      = (const float*)d_in[7];
    const float* W_ih     = (const float*)d_in[8];
    const float* W_hh     = (const float*)d_in[9];
    const float* b_ih     = (const float*)d_in[10];
    const float* b_hh     = (const float*)d_in[11];
    const float* W_init_h = (const float*)d_in[12];
    const float* b_init_h = (const float*)d_in[13];
    const float* W_init_c = (const float*)d_in[14];
    const float* b_init_c = (const float*)d_in[15];
    const float* W_out    = (const float*)d_in[16];
    const float* b_out    = (const float*)d_in[17];
    float* out = (float*)d_out;
    float* ws  = (float*)d_ws;

    // workspace layout (float slots): total 6,881,280 fl = 27.5 MB (as R10)
    float* hT  = ws;                                   // 65,536  ping-pong [j][b]
    float* cB  = ws + 65536;                           // 32,768  [b][j]
    float* dTb = ws + 98304;                           // 32,768  [b][j]
    float* gH  = ws + 131072;                          // 131,072 [b][row]
    _Float16* encatH = (_Float16*)(ws + 262144);       // 3136*512 halves
    _Float16* embgH  = (_Float16*)(ws + 1064960);      // 2048*2048 halves
    _Float16* G      = (_Float16*)(ws + 3162112);      // 3136*2048 halves
    _Float16* Hh     = (_Float16*)(ws + 6373376);      // 1984*512 halves

    float* avg = dTb;    // pre-phase alias (dead before decode)

    dim3 thr(256);

    // ---- pre-phase (R10-exact) ----
    k_avg<<<128, thr, 0, stream>>>(feat, avg);
    // h0: write hT[j][b] directly via transposed store
    gemm_nt_f32<<<dim3(8, 1), thr, 0, stream>>>(avg, 512, W_init_h, 512, b_init_h, nullptr,
                                                nullptr, 0, 64, 512, 512, hT, 64);
    gemm_nt_f32<<<dim3(8, 1), thr, 0, stream>>>(avg, 512, W_init_c, 512, b_init_c, nullptr,
                                                cB, 512, 64, 512, 512, nullptr, 0);
    // embgH[b*32+t][row] = caps @ W_ih[:, :512]^T + b_ih + b_hh   (f16 out)
    gemm_nt_ff<<<dim3(32, 32), thr, 0, stream>>>(caps, 512, W_ih, 1024, b_ih, b_hh,
                                                 nullptr, embgH, 2048);
    // encatH[b*49+r][j] = feat @ W_enc^T + b_enc   (f16 out)
    gemm_nt_ff<<<dim3(8, 49), thr, 0, stream>>>(feat, 512, W_enc, 512, b_enc, nullptr,
                                                nullptr, encatH, 512);
    // G[b*49+r][row] = feat @ W_ih[:, 512:]^T   (f16 out, no bias)
    gemm_nt_ff<<<dim3(32, 49), thr, 0, stream>>>(feat, 512, W_ih + 512, 1024, nullptr, nullptr,
                                                 nullptr, G, 2048);

    // ---- decode: 2 launches per step (R10-exact kernels) ----
    for (int t = 0; t < TS; ++t) {
        const float* hR = hT + (size_t)(t & 1) * (H_ * 64);
        float*       hN = hT + (size_t)((t + 1) & 1) * (H_ * 64);
        kA<<<256, thr, 0, stream>>>(hR, W_dec, b_dec, W_hh, dTb, gH);
        kB<<<64, thr, 0, stream>>>(dTb, encatH, v_w, v_b, G, gH, embgH, cB, hN, Hh, t);
    }

    // ---- logits: XCD-swizzled 64x256-tile f16 MFMA GEMM ----
    gemm_nt_hf_swz<<<1240, thr, 0, stream>>>(Hh, W_out, b_out, out, V_);
}

// Round 13
// 1017.040 us; speedup vs baseline: 1.0133x; 1.0133x over previous
//
#include <hip/hip_runtime.h>
#include <cstddef>

// Problem dims
#define B_  64
#define R_  49
#define F_  512
#define H_  512
#define V_  10000
#define TT  32
#define TS  31

typedef _Float16 half8 __attribute__((ext_vector_type(8)));
typedef float    f32x4 __attribute__((ext_vector_type(4)));

__device__ __forceinline__ float fsigm(float x) { return 1.0f / (1.0f + __expf(-x)); }
__device__ __forceinline__ float ftanh(float x) { return 1.0f - 2.0f / (__expf(2.0f * x) + 1.0f); }

__device__ __forceinline__ half8 cvt8(float4 a, float4 b) {
    half8 o = { (_Float16)a.x, (_Float16)a.y, (_Float16)a.z, (_Float16)a.w,
                (_Float16)b.x, (_Float16)b.y, (_Float16)b.z, (_Float16)b.w };
    return o;
}

// ---------------------------------------------------------------------------
// Generic fp32 NT GEMM (h0/c0 only). Optional Ct: also store C^T.
// ---------------------------------------------------------------------------
__global__ __launch_bounds__(256) void gemm_nt_f32(
    const float* __restrict__ A, int lda,
    const float* __restrict__ Bm, int ldb,
    const float* __restrict__ bias1, const float* __restrict__ bias2,
    float* __restrict__ C, int ldc, int M, int N, int K,
    float* __restrict__ Ct, int ldct)
{
    __shared__ __align__(16) float As[16][68];
    __shared__ __align__(16) float Bs[16][68];
    const int tid = threadIdx.x;
    const int m0 = blockIdx.y * 64, n0 = blockIdx.x * 64;
    const int tr = tid >> 4, tc = tid & 15;
    const int lrow = tid >> 2, lk4 = (tid & 3) * 4;
    const bool am = (m0 + lrow) < M;
    const bool bn = (n0 + lrow) < N;
    const float* aptr = A + (size_t)(m0 + lrow) * lda + lk4;
    const float* bptr = Bm + (size_t)(n0 + lrow) * ldb + lk4;
    float acc[4][4] = {};

    for (int k0 = 0; k0 < K; k0 += 16) {
        float4 av = make_float4(0.f, 0.f, 0.f, 0.f);
        float4 bv = make_float4(0.f, 0.f, 0.f, 0.f);
        if (am) av = *(const float4*)(aptr + k0);
        if (bn) bv = *(const float4*)(bptr + k0);
        __syncthreads();
        As[lk4 + 0][lrow] = av.x; As[lk4 + 1][lrow] = av.y;
        As[lk4 + 2][lrow] = av.z; As[lk4 + 3][lrow] = av.w;
        Bs[lk4 + 0][lrow] = bv.x; Bs[lk4 + 1][lrow] = bv.y;
        Bs[lk4 + 2][lrow] = bv.z; Bs[lk4 + 3][lrow] = bv.w;
        __syncthreads();
#pragma unroll
        for (int kk = 0; kk < 16; ++kk) {
            float4 a = *(const float4*)&As[kk][tr * 4];
            float4 b = *(const float4*)&Bs[kk][tc * 4];
            acc[0][0] += a.x * b.x; acc[0][1] += a.x * b.y; acc[0][2] += a.x * b.z; acc[0][3] += a.x * b.w;
            acc[1][0] += a.y * b.x; acc[1][1] += a.y * b.y; acc[1][2] += a.y * b.z; acc[1][3] += a.y * b.w;
            acc[2][0] += a.z * b.x; acc[2][1] += a.z * b.y; acc[2][2] += a.z * b.z; acc[2][3] += a.z * b.w;
            acc[3][0] += a.w * b.x; acc[3][1] += a.w * b.y; acc[3][2] += a.w * b.z; acc[3][3] += a.w * b.w;
        }
    }
#pragma unroll
    for (int i = 0; i < 4; ++i) {
        int m = m0 + tr * 4 + i;
        if (m >= M) continue;
#pragma unroll
        for (int j = 0; j < 4; ++j) {
            int n = n0 + tc * 4 + j;
            if (n >= N) continue;
            float v = acc[i][j];
            if (bias1) v += bias1[n];
            if (bias2) v += bias2[n];
            if (C)  C[(size_t)m * ldc + n] = v;
            if (Ct) Ct[(size_t)n * ldct + m] = v;
        }
    }
}

__global__ __launch_bounds__(256) void k_avg(const float* __restrict__ feat,
                                             float* __restrict__ avg)
{
    int id = blockIdx.x * 256 + threadIdx.x;
    int b = id >> 9, f = id & 511;
    const float* p = feat + (size_t)b * R_ * F_ + f;
    float s = 0.f;
#pragma unroll 7
    for (int r = 0; r < R_; ++r) s += p[r * F_];
    avg[id] = s * (1.0f / 49.0f);
}

// fp32 -> fp16, 8 elems/thread (contiguous)
__global__ __launch_bounds__(256) void k_cvt(const float* __restrict__ src,
                                             _Float16* __restrict__ dst, int n)
{
    int base = (blockIdx.x * 256 + threadIdx.x) * 8;
    if (base >= n) return;
    float4 a = *(const float4*)(src + base);
    float4 b = *(const float4*)(src + base + 4);
    *(half8*)(dst + base) = cvt8(a, b);
}

// ---------------------------------------------------------------------------
// Mixed NT GEMM: A fp32 [M,512] (lda), B fp32 [N,512] (ldb), cvt->f16 in-kernel,
// MFMA 16x16x32, out f16 (Ch) or fp32 (Cf), + bias1 + bias2.
// ---------------------------------------------------------------------------
__global__ __launch_bounds__(256) void gemm_nt_ff(
    const float* __restrict__ A, int lda,
    const float* __restrict__ Bm, int ldb,
    const float* __restrict__ bias1, const float* __restrict__ bias2,
    float* __restrict__ Cf, _Float16* __restrict__ Ch, int N)
{
    __shared__ __align__(16) _Float16 As[64][40];
    __shared__ __align__(16) _Float16 Bs[64][40];
    const int tid = threadIdx.x;
    const int w = tid >> 6, lane = tid & 63;
    const int m0 = blockIdx.y * 64, n0 = blockIdx.x * 64;
    const int srow = tid >> 2, sko = (tid & 3) * 8;
    const int fr = lane & 15, oct = lane >> 4;

    f32x4 acc[4];
#pragma unroll
    for (int nt = 0; nt < 4; ++nt) acc[nt] = (f32x4){0.f, 0.f, 0.f, 0.f};

    const float* ap = A + (size_t)(m0 + srow) * lda + sko;
    const float* bp = Bm + (size_t)(n0 + srow) * ldb + sko;

    for (int k0 = 0; k0 < 512; k0 += 32) {
        float4 a0 = *(const float4*)(ap + k0);
        float4 a1 = *(const float4*)(ap + k0 + 4);
        float4 b0 = *(const float4*)(bp + k0);
        float4 b1 = *(const float4*)(bp + k0 + 4);
        __syncthreads();
        *(half8*)&As[srow][sko] = cvt8(a0, a1);
        *(half8*)&Bs[srow][sko] = cvt8(b0, b1);
        __syncthreads();
        half8 af = *(const half8*)&As[w * 16 + fr][oct * 8];
#pragma unroll
        for (int nt = 0; nt < 4; ++nt) {
            half8 bf = *(const half8*)&Bs[nt * 16 + fr][oct * 8];
            acc[nt] = __builtin_amdgcn_mfma_f32_16x16x32_f16(af, bf, acc[nt], 0, 0, 0);
        }
    }
#pragma unroll
    for (int nt = 0; nt < 4; ++nt) {
        int nn = n0 + nt * 16 + fr;
        float bb = bias1 ? bias1[nn] : 0.f;
        if (bias2) bb += bias2[nn];
#pragma unroll
        for (int r = 0; r < 4; ++r) {
            int mm = m0 + w * 16 + oct * 4 + r;
            float v = acc[nt][r] + bb;
            if (Cf) Cf[(size_t)mm * N + nn] = v;
            else    Ch[(size_t)mm * N + nn] = (_Float16)v;
        }
    }
}

// ---------------------------------------------------------------------------
// Logits GEMM, XCD-swizzled 64x64 tile, BOTH operands f16 (B preconverted).
// A f16 [1984,512], B f16 [N,512]. ntile = xcd + 8*(g/31), mtile = g%31.
// (R10 structure + R8 f16-B: 1 half8 B-load, 0 cvts per k-step.)
// ---------------------------------------------------------------------------
#define MT_  31          // m-tiles (1984/64)
#define NT_  157         // n-tiles (ceil 10000/64)
__global__ __launch_bounds__(256) void gemm_nt_hh_swz(
    const _Float16* __restrict__ A, const _Float16* __restrict__ Bh,
    const float* __restrict__ bias, float* __restrict__ C, int N)
{
    const int L = blockIdx.x;
    const int xcd = L & 7, g = L >> 3;
    const int ntile = xcd + 8 * (g / MT_);
    const int mtile = g % MT_;
    if (ntile >= NT_) return;

    __shared__ __align__(16) _Float16 As[64][40];
    __shared__ __align__(16) _Float16 Bs[64][40];
    const int tid = threadIdx.x;
    const int w = tid >> 6, lane = tid & 63;
    const int m0 = mtile * 64, n0 = ntile * 64;
    const int srow = tid >> 2, sko = (tid & 3) * 8;
    const int fr = lane & 15, oct = lane >> 4;

    f32x4 acc[4];
#pragma unroll
    for (int nt = 0; nt < 4; ++nt) acc[nt] = (f32x4){0.f, 0.f, 0.f, 0.f};

    const bool bok = (n0 + srow) < N;
    const _Float16* ap = A + (size_t)(m0 + srow) * 512 + sko;
    const _Float16* bp = Bh + (size_t)(n0 + srow) * 512 + sko;

    for (int k0 = 0; k0 < 512; k0 += 32) {
        half8 av = *(const half8*)(ap + k0);
        half8 bv = {0, 0, 0, 0, 0, 0, 0, 0};
        if (bok) bv = *(const half8*)(bp + k0);
        __syncthreads();
        *(half8*)&As[srow][sko] = av;
        *(half8*)&Bs[srow][sko] = bv;
        __syncthreads();
        half8 af = *(const half8*)&As[w * 16 + fr][oct * 8];
#pragma unroll
        for (int nt = 0; nt < 4; ++nt) {
            half8 bf = *(const half8*)&Bs[nt * 16 + fr][oct * 8];
            acc[nt] = __builtin_amdgcn_mfma_f32_16x16x32_f16(af, bf, acc[nt], 0, 0, 0);
        }
    }
#pragma unroll
    for (int nt = 0; nt < 4; ++nt) {
        int nn = n0 + nt * 16 + fr;
        if (nn >= N) continue;
        float bb = bias[nn];
#pragma unroll
        for (int r = 0; r < 4; ++r) {
            int mm = m0 + w * 16 + oct * 4 + r;
            C[(size_t)mm * N + nn] = acc[nt][r] + bb;
        }
    }
}

// ---------------------------------------------------------------------------
// K_A (j-parallel, 256 blocks x 256 threads): R10-exact.
// ---------------------------------------------------------------------------
__global__ __launch_bounds__(256) void kA(
    const float* __restrict__ hT, const float* __restrict__ W_dec,
    const float* __restrict__ b_dec, const float* __restrict__ W_hh,
    float* __restrict__ dTb, float* __restrict__ gH)
{
    __shared__ __align__(16) float wpan[10 * 512];   // 20 KB
    __shared__ float red[4][640];                    // 10 KB
    const int tid = threadIdx.x, bid = blockIdx.x;
    const int lane = tid & 63, w = tid >> 6;

    for (int idx = tid * 4; idx < 10 * 512; idx += 1024) {
        int r = idx >> 9, k = idx & 511;
        const float* src = (r < 8) ? &W_hh[(size_t)(8 * bid + r) * 512 + k]
                                   : &W_dec[(size_t)(2 * bid + r - 8) * 512 + k];
        *(float4*)&wpan[idx] = *(const float4*)src;
    }
    __syncthreads();
    float acc[10] = {};
    for (int j4 = 32 * w; j4 < 32 * w + 32; ++j4) {
        int j = j4 * 4;
        float x0 = hT[(j + 0) * 64 + lane];
        float x1 = hT[(j + 1) * 64 + lane];
        float x2 = hT[(j + 2) * 64 + lane];
        float x3 = hT[(j + 3) * 64 + lane];
#pragma unroll
        for (int r = 0; r < 10; ++r) {
            float4 wv = *(const float4*)&wpan[r * 512 + j];
            acc[r] += wv.x * x0 + wv.y * x1 + wv.z * x2 + wv.w * x3;
        }
    }
#pragma unroll
    for (int r = 0; r < 10; ++r) red[w][r * 64 + lane] = acc[r];
    __syncthreads();
    for (int o = tid; o < 640; o += 256) {
        int r = o >> 6, b = o & 63;
        float s = red[0][o] + red[1][o] + red[2][o] + red[3][o];
        if (r < 8) gH[(size_t)b * 2048 + 8 * bid + r] = s;
        else       dTb[(size_t)b * 512 + 2 * bid + (r - 8)] = s + b_dec[2 * bid + r - 8];
    }
}

// ---------------------------------------------------------------------------
// K_B (b-parallel, 64 blocks x 256 threads): R10-exact.
// ---------------------------------------------------------------------------
__global__ __launch_bounds__(256) void kB(
    const float* __restrict__ dTb, const _Float16* __restrict__ encatH,
    const float* __restrict__ v_w, const float* __restrict__ v_b,
    const _Float16* __restrict__ G, const float* __restrict__ gH,
    const _Float16* __restrict__ embgH, float* __restrict__ cB,
    float* __restrict__ hTn, _Float16* __restrict__ Hh, int t)
{
    __shared__ float da[512];
    __shared__ float esh[52];
    __shared__ float al[52];
    __shared__ float gsm[2048];
    const int tid = threadIdx.x, b = blockIdx.x;
    const int lane = tid & 63, w = tid >> 6;

    da[tid]       = dTb[(size_t)b * 512 + tid];
    da[tid + 256] = dTb[(size_t)b * 512 + tid + 256];
    __syncthreads();

    for (int r = w; r < R_; r += 4) {
        const _Float16* er = encatH + ((size_t)b * R_ + r) * 512;
        float s = 0.f;
#pragma unroll
        for (int i = 0; i < 8; ++i) {
            int j = i * 64 + lane;
            s += ftanh((float)er[j] + da[j]) * v_w[j];
        }
#pragma unroll
        for (int off = 32; off; off >>= 1) s += __shfl_down(s, off, 64);
        if (lane == 0) esh[r] = s + v_b[0];
    }
    __syncthreads();
    if (tid < 64) {
        float x = (lane < R_) ? esh[lane] : -1e30f;
        float mx = x;
#pragma unroll
        for (int off = 32; off; off >>= 1) mx = fmaxf(mx, __shfl_xor(mx, off, 64));
        float ex = (lane < R_) ? __expf(x - mx) : 0.f;
        float sm = ex;
#pragma unroll
        for (int off = 32; off; off >>= 1) sm += __shfl_xor(sm, off, 64);
        if (lane < R_) al[lane] = ex / sm;
    }
    __syncthreads();

    // gates: rows [tid*8, tid*8+8)
    {
        const int r0 = tid * 8;
        float a8[8] = {};
        const _Float16* gp = G + ((size_t)b * R_) * 2048 + r0;
        for (int r = 0; r < R_; ++r) {
            half8 g8 = *(const half8*)(gp + (size_t)r * 2048);
            float ar = al[r];
#pragma unroll
            for (int u = 0; u < 8; ++u) a8[u] += ar * (float)g8[u];
        }
        float4 gh0 = *(const float4*)&gH[(size_t)b * 2048 + r0];
        float4 gh1 = *(const float4*)&gH[(size_t)b * 2048 + r0 + 4];
        half8 e8 = *(const half8*)&embgH[((size_t)b * TT + t) * 2048 + r0];
        gsm[r0 + 0] = a8[0] + gh0.x + (float)e8[0];
        gsm[r0 + 1] = a8[1] + gh0.y + (float)e8[1];
        gsm[r0 + 2] = a8[2] + gh0.z + (float)e8[2];
        gsm[r0 + 3] = a8[3] + gh0.w + (float)e8[3];
        gsm[r0 + 4] = a8[4] + gh1.x + (float)e8[4];
        gsm[r0 + 5] = a8[5] + gh1.y + (float)e8[5];
        gsm[r0 + 6] = a8[6] + gh1.z + (float)e8[6];
        gsm[r0 + 7] = a8[7] + gh1.w + (float)e8[7];
    }
    __syncthreads();

#pragma unroll
    for (int p = 0; p < 2; ++p) {
        int j = tid + p * 256;
        float ig = fsigm(gsm[j]);
        float fg = fsigm(gsm[512 + j]);
        float gg = ftanh(gsm[1024 + j]);
        float og = fsigm(gsm[1536 + j]);
        float c  = cB[(size_t)b * 512 + j];
        float cn = fg * c + ig * gg;
        float hn = og * ftanh(cn);
        cB[(size_t)b * 512 + j] = cn;
        hTn[(size_t)j * 64 + b] = hn;
        Hh[((size_t)b * TS + t) * 512 + j] = (_Float16)hn;
    }
}

// ---------------------------------------------------------------------------
extern "C" void kernel_launch(void* const* d_in, const int* in_sizes, int n_in,
                              void* d_out, int out_size, void* d_ws, size_t ws_size,
                              hipStream_t stream)
{
    (void)in_sizes; (void)n_in; (void)out_size; (void)ws_size;
    const float* feat     = (const float*)d_in[0];
    const float* caps     = (const float*)d_in[1];
    const float* W_enc    = (const float*)d_in[2];
    const float* b_enc    = (const float*)d_in[3];
    const float* W_dec    = (const float*)d_in[4];
    const float* b_dec    = (const float*)d_in[5];
    const float* v_w      = (const float*)d_in[6];
    const float* v_b      = (const float*)d_in[7];
    const float* W_ih     = (const float*)d_in[8];
    const float* W_hh     = (const float*)d_in[9];
    const float* b_ih     = (const float*)d_in[10];
    const float* b_hh     = (const float*)d_in[11];
    const float* W_init_h = (const float*)d_in[12];
    const float* b_init_h = (const float*)d_in[13];
    const float* W_init_c = (const float*)d_in[14];
    const float* b_init_c = (const float*)d_in[15];
    const float* W_out    = (const float*)d_in[16];
    const float* b_out    = (const float*)d_in[17];
    float* out = (float*)d_out;
    float* ws  = (float*)d_ws;

    // workspace layout (float slots): total 6,881,280 fl = 27.5 MB (as R10/R12)
    float* hT  = ws;                                   // 65,536  ping-pong [j][b]
    float* cB  = ws + 65536;                           // 32,768  [b][j]
    float* dTb = ws + 98304;                           // 32,768  [b][j]
    float* gH  = ws + 131072;                          // 131,072 [b][row]
    _Float16* encatH = (_Float16*)(ws + 262144);       // 3136*512 halves
    _Float16* embgH  = (_Float16*)(ws + 1064960);      // 2048*2048 halves
    _Float16* G      = (_Float16*)(ws + 3162112);      // 3136*2048 halves
    _Float16* Hh     = (_Float16*)(ws + 6373376);      // 1984*512 halves

    float* avg = dTb;    // pre-phase alias (dead before decode)
    // Wh (10000*512 halves = 2,560,000 fl) aliases encatH+embgH region
    // (both dead after the decode loop; region spans 2,899,968 fl >= needed).
    _Float16* Wh = (_Float16*)(ws + 262144);

    dim3 thr(256);

    // ---- pre-phase (R12-exact) ----
    k_avg<<<128, thr, 0, stream>>>(feat, avg);
    gemm_nt_f32<<<dim3(8, 1), thr, 0, stream>>>(avg, 512, W_init_h, 512, b_init_h, nullptr,
                                                nullptr, 0, 64, 512, 512, hT, 64);
    gemm_nt_f32<<<dim3(8, 1), thr, 0, stream>>>(avg, 512, W_init_c, 512, b_init_c, nullptr,
                                                cB, 512, 64, 512, 512, nullptr, 0);
    gemm_nt_ff<<<dim3(32, 32), thr, 0, stream>>>(caps, 512, W_ih, 1024, b_ih, b_hh,
                                                 nullptr, embgH, 2048);
    gemm_nt_ff<<<dim3(8, 49), thr, 0, stream>>>(feat, 512, W_enc, 512, b_enc, nullptr,
                                                nullptr, encatH, 512);
    gemm_nt_ff<<<dim3(32, 49), thr, 0, stream>>>(feat, 512, W_ih + 512, 1024, nullptr, nullptr,
                                                 nullptr, G, 2048);

    // ---- decode: 2 launches per step (R10/R12-exact kernels) ----
    for (int t = 0; t < TS; ++t) {
        const float* hR = hT + (size_t)(t & 1) * (H_ * 64);
        float*       hN = hT + (size_t)((t + 1) & 1) * (H_ * 64);
        kA<<<256, thr, 0, stream>>>(hR, W_dec, b_dec, W_hh, dTb, gH);
        kB<<<64, thr, 0, stream>>>(dTb, encatH, v_w, v_b, G, gH, embgH, cB, hN, Hh, t);
    }

    // ---- logits: preconvert W_out -> f16, then XCD-swizzled 64x64 f16xf16 ----
    k_cvt<<<2500, thr, 0, stream>>>(W_out, Wh, V_ * 512);
    gemm_nt_hh_swz<<<4960, thr, 0, stream>>>(Hh, Wh, b_out, out, V_);
}

// Round 14
// 1005.557 us; speedup vs baseline: 1.0249x; 1.0114x over previous
//
#include <hip/hip_runtime.h>
#include <cstddef>

// Problem dims
#define B_  64
#define R_  49
#define F_  512
#define H_  512
#define V_  10000
#define TT  32
#define TS  31

typedef _Float16 half8 __attribute__((ext_vector_type(8)));
typedef float    f32x4 __attribute__((ext_vector_type(4)));

__device__ __forceinline__ float fsigm(float x) { return 1.0f / (1.0f + __expf(-x)); }
__device__ __forceinline__ float ftanh(float x) { return 1.0f - 2.0f / (__expf(2.0f * x) + 1.0f); }

__device__ __forceinline__ half8 cvt8(float4 a, float4 b) {
    half8 o = { (_Float16)a.x, (_Float16)a.y, (_Float16)a.z, (_Float16)a.w,
                (_Float16)b.x, (_Float16)b.y, (_Float16)b.z, (_Float16)b.w };
    return o;
}

// ---------------------------------------------------------------------------
// Generic fp32 NT GEMM (h0/c0 only). Optional Ct: also store C^T.
// ---------------------------------------------------------------------------
__global__ __launch_bounds__(256) void gemm_nt_f32(
    const float* __restrict__ A, int lda,
    const float* __restrict__ Bm, int ldb,
    const float* __restrict__ bias1, const float* __restrict__ bias2,
    float* __restrict__ C, int ldc, int M, int N, int K,
    float* __restrict__ Ct, int ldct)
{
    __shared__ __align__(16) float As[16][68];
    __shared__ __align__(16) float Bs[16][68];
    const int tid = threadIdx.x;
    const int m0 = blockIdx.y * 64, n0 = blockIdx.x * 64;
    const int tr = tid >> 4, tc = tid & 15;
    const int lrow = tid >> 2, lk4 = (tid & 3) * 4;
    const bool am = (m0 + lrow) < M;
    const bool bn = (n0 + lrow) < N;
    const float* aptr = A + (size_t)(m0 + lrow) * lda + lk4;
    const float* bptr = Bm + (size_t)(n0 + lrow) * ldb + lk4;
    float acc[4][4] = {};

    for (int k0 = 0; k0 < K; k0 += 16) {
        float4 av = make_float4(0.f, 0.f, 0.f, 0.f);
        float4 bv = make_float4(0.f, 0.f, 0.f, 0.f);
        if (am) av = *(const float4*)(aptr + k0);
        if (bn) bv = *(const float4*)(bptr + k0);
        __syncthreads();
        As[lk4 + 0][lrow] = av.x; As[lk4 + 1][lrow] = av.y;
        As[lk4 + 2][lrow] = av.z; As[lk4 + 3][lrow] = av.w;
        Bs[lk4 + 0][lrow] = bv.x; Bs[lk4 + 1][lrow] = bv.y;
        Bs[lk4 + 2][lrow] = bv.z; Bs[lk4 + 3][lrow] = bv.w;
        __syncthreads();
#pragma unroll
        for (int kk = 0; kk < 16; ++kk) {
            float4 a = *(const float4*)&As[kk][tr * 4];
            float4 b = *(const float4*)&Bs[kk][tc * 4];
            acc[0][0] += a.x * b.x; acc[0][1] += a.x * b.y; acc[0][2] += a.x * b.z; acc[0][3] += a.x * b.w;
            acc[1][0] += a.y * b.x; acc[1][1] += a.y * b.y; acc[1][2] += a.y * b.z; acc[1][3] += a.y * b.w;
            acc[2][0] += a.z * b.x; acc[2][1] += a.z * b.y; acc[2][2] += a.z * b.z; acc[2][3] += a.z * b.w;
            acc[3][0] += a.w * b.x; acc[3][1] += a.w * b.y; acc[3][2] += a.w * b.z; acc[3][3] += a.w * b.w;
        }
    }
#pragma unroll
    for (int i = 0; i < 4; ++i) {
        int m = m0 + tr * 4 + i;
        if (m >= M) continue;
#pragma unroll
        for (int j = 0; j < 4; ++j) {
            int n = n0 + tc * 4 + j;
            if (n >= N) continue;
            float v = acc[i][j];
            if (bias1) v += bias1[n];
            if (bias2) v += bias2[n];
            if (C)  C[(size_t)m * ldc + n] = v;
            if (Ct) Ct[(size_t)n * ldct + m] = v;
        }
    }
}

__global__ __launch_bounds__(256) void k_avg(const float* __restrict__ feat,
                                             float* __restrict__ avg)
{
    int id = blockIdx.x * 256 + threadIdx.x;
    int b = id >> 9, f = id & 511;
    const float* p = feat + (size_t)b * R_ * F_ + f;
    float s = 0.f;
#pragma unroll 7
    for (int r = 0; r < R_; ++r) s += p[r * F_];
    avg[id] = s * (1.0f / 49.0f);
}

// fp32 -> fp16, 8 elems/thread (contiguous)
__global__ __launch_bounds__(256) void k_cvt(const float* __restrict__ src,
                                             _Float16* __restrict__ dst, int n)
{
    int base = (blockIdx.x * 256 + threadIdx.x) * 8;
    if (base >= n) return;
    float4 a = *(const float4*)(src + base);
    float4 b = *(const float4*)(src + base + 4);
    *(half8*)(dst + base) = cvt8(a, b);
}

// ---------------------------------------------------------------------------
// Mixed NT GEMM: A fp32 [M,512] (lda), B fp32 [N,512] (ldb), cvt->f16 in-kernel,
// MFMA 16x16x32, out f16 (Ch) or fp32 (Cf), + bias1 + bias2.
// ---------------------------------------------------------------------------
__global__ __launch_bounds__(256) void gemm_nt_ff(
    const float* __restrict__ A, int lda,
    const float* __restrict__ Bm, int ldb,
    const float* __restrict__ bias1, const float* __restrict__ bias2,
    float* __restrict__ Cf, _Float16* __restrict__ Ch, int N)
{
    __shared__ __align__(16) _Float16 As[64][40];
    __shared__ __align__(16) _Float16 Bs[64][40];
    const int tid = threadIdx.x;
    const int w = tid >> 6, lane = tid & 63;
    const int m0 = blockIdx.y * 64, n0 = blockIdx.x * 64;
    const int srow = tid >> 2, sko = (tid & 3) * 8;
    const int fr = lane & 15, oct = lane >> 4;

    f32x4 acc[4];
#pragma unroll
    for (int nt = 0; nt < 4; ++nt) acc[nt] = (f32x4){0.f, 0.f, 0.f, 0.f};

    const float* ap = A + (size_t)(m0 + srow) * lda + sko;
    const float* bp = Bm + (size_t)(n0 + srow) * ldb + sko;

    for (int k0 = 0; k0 < 512; k0 += 32) {
        float4 a0 = *(const float4*)(ap + k0);
        float4 a1 = *(const float4*)(ap + k0 + 4);
        float4 b0 = *(const float4*)(bp + k0);
        float4 b1 = *(const float4*)(bp + k0 + 4);
        __syncthreads();
        *(half8*)&As[srow][sko] = cvt8(a0, a1);
        *(half8*)&Bs[srow][sko] = cvt8(b0, b1);
        __syncthreads();
        half8 af = *(const half8*)&As[w * 16 + fr][oct * 8];
#pragma unroll
        for (int nt = 0; nt < 4; ++nt) {
            half8 bf = *(const half8*)&Bs[nt * 16 + fr][oct * 8];
            acc[nt] = __builtin_amdgcn_mfma_f32_16x16x32_f16(af, bf, acc[nt], 0, 0, 0);
        }
    }
#pragma unroll
    for (int nt = 0; nt < 4; ++nt) {
        int nn = n0 + nt * 16 + fr;
        float bb = bias1 ? bias1[nn] : 0.f;
        if (bias2) bb += bias2[nn];
#pragma unroll
        for (int r = 0; r < 4; ++r) {
            int mm = m0 + w * 16 + oct * 4 + r;
            float v = acc[nt][r] + bb;
            if (Cf) Cf[(size_t)mm * N + nn] = v;
            else    Ch[(size_t)mm * N + nn] = (_Float16)v;
        }
    }
}

// ---------------------------------------------------------------------------
// Logits GEMM, XCD-swizzled 64m x 128n tile, BOTH operands f16.
// A f16 [1984,512], B f16 [N,512]. 79 n-supertiles (128 wide), 31 m-tiles.
// nsup = xcd + 8*s (s = g/31) covers 0..78 exactly once (guard >=79);
// all 31 m-blocks of one supertile run consecutively on one XCD.
// 8 MFMAs per barrier pair (2x R13's amortization), acc = 32 VGPR, LDS 15KB.
// ---------------------------------------------------------------------------
#define MT_    31          // m-tiles (1984/64)
#define NPAIR_ 79          // 128-wide n-supertiles (ceil 10000/128)
__global__ __launch_bounds__(256) void gemm_nt_hh_swz2(
    const _Float16* __restrict__ A, const _Float16* __restrict__ Bh,
    const float* __restrict__ bias, float* __restrict__ C, int N)
{
    const int L = blockIdx.x;          // 0..2479 (8 x 310)
    const int xcd = L & 7, g = L >> 3;
    const int nsup = xcd + 8 * (g / MT_);
    const int mtile = g % MT_;
    if (nsup >= NPAIR_) return;

    __shared__ __align__(16) _Float16 As[64][40];
    __shared__ __align__(16) _Float16 Bs[128][40];
    const int tid = threadIdx.x;
    const int w = tid >> 6, lane = tid & 63;
    const int m0 = mtile * 64, n0 = nsup * 128;
    const int srow = tid >> 2, sko = (tid & 3) * 8;
    const int fr = lane & 15, oct = lane >> 4;

    f32x4 acc[8];
#pragma unroll
    for (int nt = 0; nt < 8; ++nt) acc[nt] = (f32x4){0.f, 0.f, 0.f, 0.f};

    const bool bok0 = (n0 + srow) < N;
    const bool bok1 = (n0 + 64 + srow) < N;
    const _Float16* ap  = A  + (size_t)(m0 + srow) * 512 + sko;
    const _Float16* bp0 = Bh + (size_t)(n0 + srow) * 512 + sko;
    const _Float16* bp1 = Bh + (size_t)(n0 + 64 + srow) * 512 + sko;

    for (int k0 = 0; k0 < 512; k0 += 32) {
        half8 av = *(const half8*)(ap + k0);
        half8 bv0 = {0, 0, 0, 0, 0, 0, 0, 0};
        half8 bv1 = {0, 0, 0, 0, 0, 0, 0, 0};
        if (bok0) bv0 = *(const half8*)(bp0 + k0);
        if (bok1) bv1 = *(const half8*)(bp1 + k0);
        __syncthreads();
        *(half8*)&As[srow][sko] = av;
        *(half8*)&Bs[srow][sko] = bv0;
        *(half8*)&Bs[64 + srow][sko] = bv1;
        __syncthreads();
        half8 af = *(const half8*)&As[w * 16 + fr][oct * 8];
#pragma unroll
        for (int nt = 0; nt < 8; ++nt) {
            half8 bf = *(const half8*)&Bs[nt * 16 + fr][oct * 8];
            acc[nt] = __builtin_amdgcn_mfma_f32_16x16x32_f16(af, bf, acc[nt], 0, 0, 0);
        }
    }
#pragma unroll
    for (int nt = 0; nt < 8; ++nt) {
        int nn = n0 + nt * 16 + fr;
        if (nn >= N) continue;
        float bb = bias[nn];
#pragma unroll
        for (int r = 0; r < 4; ++r) {
            int mm = m0 + w * 16 + oct * 4 + r;
            C[(size_t)mm * N + nn] = acc[nt][r] + bb;
        }
    }
}

// ---------------------------------------------------------------------------
// K_A (j-parallel, 256 blocks x 256 threads): R10-exact.
// ---------------------------------------------------------------------------
__global__ __launch_bounds__(256) void kA(
    const float* __restrict__ hT, const float* __restrict__ W_dec,
    const float* __restrict__ b_dec, const float* __restrict__ W_hh,
    float* __restrict__ dTb, float* __restrict__ gH)
{
    __shared__ __align__(16) float wpan[10 * 512];   // 20 KB
    __shared__ float red[4][640];                    // 10 KB
    const int tid = threadIdx.x, bid = blockIdx.x;
    const int lane = tid & 63, w = tid >> 6;

    for (int idx = tid * 4; idx < 10 * 512; idx += 1024) {
        int r = idx >> 9, k = idx & 511;
        const float* src = (r < 8) ? &W_hh[(size_t)(8 * bid + r) * 512 + k]
                                   : &W_dec[(size_t)(2 * bid + r - 8) * 512 + k];
        *(float4*)&wpan[idx] = *(const float4*)src;
    }
    __syncthreads();
    float acc[10] = {};
    for (int j4 = 32 * w; j4 < 32 * w + 32; ++j4) {
        int j = j4 * 4;
        float x0 = hT[(j + 0) * 64 + lane];
        float x1 = hT[(j + 1) * 64 + lane];
        float x2 = hT[(j + 2) * 64 + lane];
        float x3 = hT[(j + 3) * 64 + lane];
#pragma unroll
        for (int r = 0; r < 10; ++r) {
            float4 wv = *(const float4*)&wpan[r * 512 + j];
            acc[r] += wv.x * x0 + wv.y * x1 + wv.z * x2 + wv.w * x3;
        }
    }
#pragma unroll
    for (int r = 0; r < 10; ++r) red[w][r * 64 + lane] = acc[r];
    __syncthreads();
    for (int o = tid; o < 640; o += 256) {
        int r = o >> 6, b = o & 63;
        float s = red[0][o] + red[1][o] + red[2][o] + red[3][o];
        if (r < 8) gH[(size_t)b * 2048 + 8 * bid + r] = s;
        else       dTb[(size_t)b * 512 + 2 * bid + (r - 8)] = s + b_dec[2 * bid + r - 8];
    }
}

// ---------------------------------------------------------------------------
// K_B (b-parallel, 64 blocks x 256 threads): R10-exact.
// ---------------------------------------------------------------------------
__global__ __launch_bounds__(256) void kB(
    const float* __restrict__ dTb, const _Float16* __restrict__ encatH,
    const float* __restrict__ v_w, const float* __restrict__ v_b,
    const _Float16* __restrict__ G, const float* __restrict__ gH,
    const _Float16* __restrict__ embgH, float* __restrict__ cB,
    float* __restrict__ hTn, _Float16* __restrict__ Hh, int t)
{
    __shared__ float da[512];
    __shared__ float esh[52];
    __shared__ float al[52];
    __shared__ float gsm[2048];
    const int tid = threadIdx.x, b = blockIdx.x;
    const int lane = tid & 63, w = tid >> 6;

    da[tid]       = dTb[(size_t)b * 512 + tid];
    da[tid + 256] = dTb[(size_t)b * 512 + tid + 256];
    __syncthreads();

    for (int r = w; r < R_; r += 4) {
        const _Float16* er = encatH + ((size_t)b * R_ + r) * 512;
        float s = 0.f;
#pragma unroll
        for (int i = 0; i < 8; ++i) {
            int j = i * 64 + lane;
            s += ftanh((float)er[j] + da[j]) * v_w[j];
        }
#pragma unroll
        for (int off = 32; off; off >>= 1) s += __shfl_down(s, off, 64);
        if (lane == 0) esh[r] = s + v_b[0];
    }
    __syncthreads();
    if (tid < 64) {
        float x = (lane < R_) ? esh[lane] : -1e30f;
        float mx = x;
#pragma unroll
        for (int off = 32; off; off >>= 1) mx = fmaxf(mx, __shfl_xor(mx, off, 64));
        float ex = (lane < R_) ? __expf(x - mx) : 0.f;
        float sm = ex;
#pragma unroll
        for (int off = 32; off; off >>= 1) sm += __shfl_xor(sm, off, 64);
        if (lane < R_) al[lane] = ex / sm;
    }
    __syncthreads();

    // gates: rows [tid*8, tid*8+8)
    {
        const int r0 = tid * 8;
        float a8[8] = {};
        const _Float16* gp = G + ((size_t)b * R_) * 2048 + r0;
        for (int r = 0; r < R_; ++r) {
            half8 g8 = *(const half8*)(gp + (size_t)r * 2048);
            float ar = al[r];
#pragma unroll
            for (int u = 0; u < 8; ++u) a8[u] += ar * (float)g8[u];
        }
        float4 gh0 = *(const float4*)&gH[(size_t)b * 2048 + r0];
        float4 gh1 = *(const float4*)&gH[(size_t)b * 2048 + r0 + 4];
        half8 e8 = *(const half8*)&embgH[((size_t)b * TT + t) * 2048 + r0];
        gsm[r0 + 0] = a8[0] + gh0.x + (float)e8[0];
        gsm[r0 + 1] = a8[1] + gh0.y + (float)e8[1];
        gsm[r0 + 2] = a8[2] + gh0.z + (float)e8[2];
        gsm[r0 + 3] = a8[3] + gh0.w + (float)e8[3];
        gsm[r0 + 4] = a8[4] + gh1.x + (float)e8[4];
        gsm[r0 + 5] = a8[5] + gh1.y + (float)e8[5];
        gsm[r0 + 6] = a8[6] + gh1.z + (float)e8[6];
        gsm[r0 + 7] = a8[7] + gh1.w + (float)e8[7];
    }
    __syncthreads();

#pragma unroll
    for (int p = 0; p < 2; ++p) {
        int j = tid + p * 256;
        float ig = fsigm(gsm[j]);
        float fg = fsigm(gsm[512 + j]);
        float gg = ftanh(gsm[1024 + j]);
        float og = fsigm(gsm[1536 + j]);
        float c  = cB[(size_t)b * 512 + j];
        float cn = fg * c + ig * gg;
        float hn = og * ftanh(cn);
        cB[(size_t)b * 512 + j] = cn;
        hTn[(size_t)j * 64 + b] = hn;
        Hh[((size_t)b * TS + t) * 512 + j] = (_Float16)hn;
    }
}

// ---------------------------------------------------------------------------
extern "C" void kernel_launch(void* const* d_in, const int* in_sizes, int n_in,
                              void* d_out, int out_size, void* d_ws, size_t ws_size,
                              hipStream_t stream)
{
    (void)in_sizes; (void)n_in; (void)out_size; (void)ws_size;
    const float* feat     = (const float*)d_in[0];
    const float* caps     = (const float*)d_in[1];
    const float* W_enc    = (const float*)d_in[2];
    const float* b_enc    = (const float*)d_in[3];
    const float* W_dec    = (const float*)d_in[4];
    const float* b_dec    = (const float*)d_in[5];
    const float* v_w      = (const float*)d_in[6];
    const float* v_b      = (const float*)d_in[7];
    const float* W_ih     = (const float*)d_in[8];
    const float* W_hh     = (const float*)d_in[9];
    const float* b_ih     = (const float*)d_in[10];
    const float* b_hh     = (const float*)d_in[11];
    const float* W_init_h = (const float*)d_in[12];
    const float* b_init_h = (const float*)d_in[13];
    const float* W_init_c = (const float*)d_in[14];
    const float* b_init_c = (const float*)d_in[15];
    const float* W_out    = (const float*)d_in[16];
    const float* b_out    = (const float*)d_in[17];
    float* out = (float*)d_out;
    float* ws  = (float*)d_ws;

    // workspace layout (float slots): total 6,881,280 fl = 27.5 MB (as R13)
    float* hT  = ws;                                   // 65,536  ping-pong [j][b]
    float* cB  = ws + 65536;                           // 32,768  [b][j]
    float* dTb = ws + 98304;                           // 32,768  [b][j]
    float* gH  = ws + 131072;                          // 131,072 [b][row]
    _Float16* encatH = (_Float16*)(ws + 262144);       // 3136*512 halves
    _Float16* embgH  = (_Float16*)(ws + 1064960);      // 2048*2048 halves
    _Float16* G      = (_Float16*)(ws + 3162112);      // 3136*2048 halves
    _Float16* Hh     = (_Float16*)(ws + 6373376);      // 1984*512 halves

    float* avg = dTb;    // pre-phase alias (dead before decode)
    // Wh (10000*512 halves) aliases encatH+embgH region (dead after decode).
    _Float16* Wh = (_Float16*)(ws + 262144);

    dim3 thr(256);

    // ---- pre-phase (R13-exact) ----
    k_avg<<<128, thr, 0, stream>>>(feat, avg);
    gemm_nt_f32<<<dim3(8, 1), thr, 0, stream>>>(avg, 512, W_init_h, 512, b_init_h, nullptr,
                                                nullptr, 0, 64, 512, 512, hT, 64);
    gemm_nt_f32<<<dim3(8, 1), thr, 0, stream>>>(avg, 512, W_init_c, 512, b_init_c, nullptr,
                                                cB, 512, 64, 512, 512, nullptr, 0);
    gemm_nt_ff<<<dim3(32, 32), thr, 0, stream>>>(caps, 512, W_ih, 1024, b_ih, b_hh,
                                                 nullptr, embgH, 2048);
    gemm_nt_ff<<<dim3(8, 49), thr, 0, stream>>>(feat, 512, W_enc, 512, b_enc, nullptr,
                                                nullptr, encatH, 512);
    gemm_nt_ff<<<dim3(32, 49), thr, 0, stream>>>(feat, 512, W_ih + 512, 1024, nullptr, nullptr,
                                                 nullptr, G, 2048);

    // ---- decode: 2 launches per step (R10/R12-exact kernels) ----
    for (int t = 0; t < TS; ++t) {
        const float* hR = hT + (size_t)(t & 1) * (H_ * 64);
        float*       hN = hT + (size_t)((t + 1) & 1) * (H_ * 64);
        kA<<<256, thr, 0, stream>>>(hR, W_dec, b_dec, W_hh, dTb, gH);
        kB<<<64, thr, 0, stream>>>(dTb, encatH, v_w, v_b, G, gH, embgH, cB, hN, Hh, t);
    }

    // ---- logits: preconvert W_out -> f16, then XCD-swizzled 64x128 f16xf16 ----
    k_cvt<<<2500, thr, 0, stream>>>(W_out, Wh, V_ * 512);
    gemm_nt_hh_swz2<<<2480, thr, 0, stream>>>(Hh, Wh, b_out, out, V_);
}